// Round 12
// baseline (213.707 us; speedup 1.0000x reference)
//
#include <hip/hip_runtime.h>
#include <hip/hip_bf16.h>
#include <math.h>

#define HW    16384
#define Bsz   4
#define CIN   32
#define COUT  64
#define RED   16
#define KKN   49
#define GG    4
#define PW    134           // padded width/height (128 + 2*3)
#define PPLANE (PW*PW)
#define N16PAD 574592       // uint4 count of x1pad

typedef __hip_bfloat16 bf16;

__device__ __forceinline__ float gelu_f(float x) {
    return 0.5f * x * (1.0f + erff(x * 0.70710678118654752f));
}
__device__ __forceinline__ void unpack_bf2(unsigned u, float& lo, float& hi) {
    lo = __uint_as_float(u << 16);
    hi = __uint_as_float(u & 0xffff0000u);
}
__device__ __forceinline__ unsigned pack_bf2(float lo, float hi) {
    unsigned a = __float_as_uint(lo), b = __float_as_uint(hi);
    a += 0x7fff + ((a >> 16) & 1);
    b += 0x7fff + ((b >> 16) & 1);
    return (a >> 16) | (b & 0xffff0000u);
}

// ---- workspace layout (bytes) ----
#define OFF_RBUF  9437184
#define OFF_X2B   13631488
#define OFF_PAR   22020096
#define PW1T 0
#define PWRT 2048
#define PW2T (2048+1024)
#define PWMT (2048+1024+4096)
#define PRSH (2048+1024+4096+2048)
#define PSHC (PRSH+16)
#define PSMV (PSHC+64)
#define PSC1 (PSMV+64)
#define PSH1 (PSC1+64)

// fused init: block 0 does weight prep; remaining blocks zero x1pad halo buffer
__global__ __launch_bounds__(256) void k0_init(
    const float* __restrict__ w1, const float* __restrict__ wr,
    const float* __restrict__ gr, const float* __restrict__ br,
    const float* __restrict__ mr, const float* __restrict__ vr,
    const float* __restrict__ g1, const float* __restrict__ b1,
    const float* __restrict__ m1, const float* __restrict__ v1,
    const float* __restrict__ w2, const float* __restrict__ g2,
    const float* __restrict__ b2, const float* __restrict__ m2,
    const float* __restrict__ v2,
    const float* __restrict__ wm, const float* __restrict__ bmap,
    const float* __restrict__ gm, const float* __restrict__ betam,
    const float* __restrict__ mm, const float* __restrict__ vm,
    float* __restrict__ par, uint4* __restrict__ x1pad)
{
    if (blockIdx.x != 0) {
        int i = (blockIdx.x - 1) * 256 + threadIdx.x;
        if (i < N16PAD) x1pad[i] = make_uint4(0u, 0u, 0u, 0u);
        return;
    }
    int t = threadIdx.x;
    for (int i = t; i < 2048; i += 256) {
        int c = i >> 6, o = i & 63;
        par[PW1T + i] = w1[o * CIN + c];
    }
    for (int i = t; i < 1024; i += 256) {
        int c = i >> 4, j = i & 15;
        float sc = gr[j] * rsqrtf(vr[j] + 1e-5f);
        par[PWRT + i] = wr[j * COUT + c] * sc;
    }
    for (int i = t; i < 4096; i += 256) {
        int c = i >> 6, o = i & 63;
        float s2 = g2[o] * rsqrtf(v2[o] + 1e-5f);
        float sm = gm[o] * rsqrtf(vm[o] + 1e-5f);
        par[PW2T + i] = w2[o * COUT + c] * (s2 / sm);
    }
    for (int i = t; i < 2048; i += 256) {
        int c = i >> 6, o = i & 63;
        par[PWMT + i] = wm[o * CIN + c];
    }
    if (t < 16) {
        float sc = gr[t] * rsqrtf(vr[t] + 1e-5f);
        par[PRSH + t] = br[t] - mr[t] * sc;
    }
    if (t < 64) {
        float s2 = g2[t] * rsqrtf(v2[t] + 1e-5f);
        float sm = gm[t] * rsqrtf(vm[t] + 1e-5f);
        par[PSHC + t] = (b2[t] - m2[t] * s2) + (betam[t] + (bmap[t] - mm[t]) * sm);
        par[PSMV + t] = sm;
        float s1 = g1[t] * rsqrtf(v1[t] + 1e-5f);
        par[PSC1 + t] = s1;
        par[PSH1 + t] = b1[t] - m1[t] * s1;
    }
}

// K1: 2 px/thread. 32 FMA per s_load_dwordx16 weight row.
__global__ __launch_bounds__(256, 2) void k1_conv1_gelu_reduce(
    const float* __restrict__ x, const float* __restrict__ par,
    unsigned* __restrict__ x1pad, float* __restrict__ rbuf)
{
    __shared__ float g_lds[COUT][130];

    int lane  = threadIdx.x & 63;
    int chunk = __builtin_amdgcn_readfirstlane(threadIdx.x >> 6);  // == group
    int b     = blockIdx.x >> 7;                 // 128 blocks per batch
    int pbase = (blockIdx.x & 127) << 7;         // 128 px per block
    int p0    = pbase + lane * 2;
    int h = p0 >> 7, w = p0 & 127;               // both px on same row

    float acc[32];
#pragma unroll
    for (int i = 0; i < 32; ++i) acc[i] = 0.f;
#pragma unroll 4
    for (int c = 0; c < CIN; ++c) {
        float2 xc = *(const float2*)&x[(b * CIN + c) * HW + p0];
        const float* wrow = par + PW1T + c * 64 + chunk * 16;
#pragma unroll
        for (int o = 0; o < 16; ++o) {
            float wv = wrow[o];
            acc[2 * o]     += xc.x * wv;
            acc[2 * o + 1] += xc.y * wv;
        }
    }

    unsigned pk[16];
#pragma unroll
    for (int o = 0; o < 16; ++o) {
        float ga = gelu_f(acc[2 * o]);
        float gb = gelu_f(acc[2 * o + 1]);
        g_lds[chunk * 16 + o][lane * 2]     = ga;
        g_lds[chunk * 16 + o][lane * 2 + 1] = gb;
        acc[2 * o] = ga; acc[2 * o + 1] = gb;
    }
    // interleave: px0 channels -> pk[0..7], px1 channels -> pk[8..15]
#pragma unroll
    for (int d = 0; d < 8; ++d) {
        pk[d]     = pack_bf2(acc[4 * d], acc[4 * d + 2]);       // px0: c2d,c2d+1
        pk[8 + d] = pack_bf2(acc[4 * d + 1], acc[4 * d + 3]);   // px1
    }
    unsigned* xo = x1pad + ((size_t)((b * GG + chunk) * PW + (h + 3)) * PW + (w + 3)) * 8;
    *(uint4*)xo        = make_uint4(pk[0], pk[1], pk[2], pk[3]);
    *(uint4*)(xo + 4)  = make_uint4(pk[4], pk[5], pk[6], pk[7]);
    *(uint4*)(xo + 8)  = make_uint4(pk[8], pk[9], pk[10], pk[11]);
    *(uint4*)(xo + 12) = make_uint4(pk[12], pk[13], pk[14], pk[15]);

    __syncthreads();

    // reduce branch: px A = pbase+lane, px B = pbase+64+lane
    float ra[4] = {0.f, 0.f, 0.f, 0.f}, rb[4] = {0.f, 0.f, 0.f, 0.f};
#pragma unroll 4
    for (int c = 0; c < COUT; ++c) {
        float ga = g_lds[c][lane];
        float gb = g_lds[c][64 + lane];
        const float* wrow = par + PWRT + c * 16 + chunk * 4;
#pragma unroll
        for (int jj = 0; jj < 4; ++jj) {
            float wv = wrow[jj];
            ra[jj] += ga * wv;
            rb[jj] += gb * wv;
        }
    }
    float ta[4], tb[4];
#pragma unroll
    for (int jj = 0; jj < 4; ++jj) {
        float sh = par[PRSH + chunk * 4 + jj];
        ta[jj] = fmaxf(ra[jj] + sh, 0.f);
        tb[jj] = fmaxf(rb[jj] + sh, 0.f);
    }
    *(float4*)&rbuf[((size_t)b * HW + pbase + lane) * 16 + chunk * 4] =
        make_float4(ta[0], ta[1], ta[2], ta[3]);
    *(float4*)&rbuf[((size_t)b * HW + pbase + 64 + lane) * 16 + chunk * 4] =
        make_float4(tb[0], tb[1], tb[2], tb[3]);
}

// K23: unchanged from round 11 (runtime tap loops, zero halo, ~20 us).
__global__ __launch_bounds__(256, 4) void k23_involution(
    const unsigned* __restrict__ x1pad, const float* __restrict__ rbuf,
    const float* __restrict__ wsp, const float* __restrict__ bsp,
    const float* __restrict__ par, unsigned* __restrict__ x2b)
{
    int bg = blockIdx.x >> 6;
    int g = bg & 3, b = bg >> 2;
    int p = ((blockIdx.x & 63) << 8) + threadIdx.x;
    int h = p >> 7, w0 = p & 127;

    float r[RED];
    {
        const float4* rp = (const float4*)&rbuf[((size_t)b * HW + p) * 16];
        float4 r0 = rp[0], r1 = rp[1], r2 = rp[2], r3 = rp[3];
        r[0]=r0.x; r[1]=r0.y; r[2]=r0.z; r[3]=r0.w;
        r[4]=r1.x; r[5]=r1.y; r[6]=r1.z; r[7]=r1.w;
        r[8]=r2.x; r[9]=r2.y; r[10]=r2.z; r[11]=r2.w;
        r[12]=r3.x; r[13]=r3.y; r[14]=r3.z; r[15]=r3.w;
    }

    const float* wrow = wsp + g * KKN * RED;
    const float* brow = bsp + g * KKN;
    const unsigned* base = x1pad + ((size_t)(bg * PW + h) * PW + w0) * 8;

    float acc[RED];
#pragma unroll
    for (int c = 0; c < RED; ++c) acc[c] = 0.f;

#pragma unroll 1
    for (int i = 0; i < 7; ++i) {
#pragma unroll 1
        for (int j = 0; j < 7; ++j) {
            int k = i * 7 + j;
            const float* wk_row = wrow + k * RED;
            float s = brow[k];
#pragma unroll
            for (int jj = 0; jj < RED; ++jj) s += r[jj] * wk_row[jj];
            const unsigned* tp = base + (size_t)(i * PW + j) * 8;
            uint4 A = *(const uint4*)tp;
            uint4 B = *(const uint4*)(tp + 4);
            float lo, hi;
            unpack_bf2(A.x, lo, hi); acc[0] += s*lo; acc[1] += s*hi;
            unpack_bf2(A.y, lo, hi); acc[2] += s*lo; acc[3] += s*hi;
            unpack_bf2(A.z, lo, hi); acc[4] += s*lo; acc[5] += s*hi;
            unpack_bf2(A.w, lo, hi); acc[6] += s*lo; acc[7] += s*hi;
            unpack_bf2(B.x, lo, hi); acc[8] += s*lo; acc[9] += s*hi;
            unpack_bf2(B.y, lo, hi); acc[10]+= s*lo; acc[11]+= s*hi;
            unpack_bf2(B.z, lo, hi); acc[12]+= s*lo; acc[13]+= s*hi;
            unpack_bf2(B.w, lo, hi); acc[14]+= s*lo; acc[15]+= s*hi;
        }
    }

    unsigned pk[8];
#pragma unroll
    for (int d = 0; d < 8; ++d) {
        int ch0 = g * RED + 2 * d, ch1 = ch0 + 1;
        float v0 = gelu_f(par[PSC1 + ch0] * acc[2 * d]     + par[PSH1 + ch0]);
        float v1 = gelu_f(par[PSC1 + ch1] * acc[2 * d + 1] + par[PSH1 + ch1]);
        pk[d] = pack_bf2(v0, v1);
    }
    unsigned* xo = x2b + ((size_t)bg * HW + p) * 8;
    *(uint4*)xo       = make_uint4(pk[0], pk[1], pk[2], pk[3]);
    *(uint4*)(xo + 4) = make_uint4(pk[4], pk[5], pk[6], pk[7]);
}

// K4: 2 px/thread, contiguous weight rows (s_load_dwordx16), acc[32].
__global__ __launch_bounds__(256, 2) void k4_final(
    const unsigned* __restrict__ x2b, const float* __restrict__ x,
    const float* __restrict__ par, float* __restrict__ out)
{
    int lane  = threadIdx.x & 63;
    int chunk = __builtin_amdgcn_readfirstlane(threadIdx.x >> 6);
    int b     = blockIdx.x >> 7;
    int p0    = ((blockIdx.x & 127) << 7) + lane * 2;

    float acc[32];
#pragma unroll
    for (int i = 0; i < 32; ++i) acc[i] = 0.f;

#pragma unroll
    for (int gg = 0; gg < GG; ++gg) {
        const unsigned* up = x2b + ((size_t)(b * GG + gg) * HW + p0) * 8;
        uint4 A0 = *(const uint4*)up;          // px0 c0..7
        uint4 B0 = *(const uint4*)(up + 4);    // px0 c8..15
        uint4 A1 = *(const uint4*)(up + 8);    // px1 c0..7
        uint4 B1 = *(const uint4*)(up + 12);   // px1 c8..15
        unsigned u0[8] = {A0.x, A0.y, A0.z, A0.w, B0.x, B0.y, B0.z, B0.w};
        unsigned u1[8] = {A1.x, A1.y, A1.z, A1.w, B1.x, B1.y, B1.z, B1.w};
#pragma unroll
        for (int d = 0; d < 8; ++d) {
            float a0, a1, b0v, b1v;
            unpack_bf2(u0[d], a0, a1);   // px0: c = 2d, 2d+1
            unpack_bf2(u1[d], b0v, b1v); // px1
            int c0 = gg * 16 + 2 * d;
            const float* wr0 = par + PW2T + c0 * 64 + chunk * 16;
            const float* wr1 = wr0 + 64;
#pragma unroll
            for (int o = 0; o < 16; ++o) {
                float w0v = wr0[o], w1v = wr1[o];
                acc[2 * o]     += a0 * w0v + a1 * w1v;
                acc[2 * o + 1] += b0v * w0v + b1v * w1v;
            }
        }
    }
#pragma unroll 4
    for (int c = 0; c < CIN; ++c) {
        float2 xc = *(const float2*)&x[(b * CIN + c) * HW + p0];
        const float* wrow = par + PWMT + c * 64 + chunk * 16;
#pragma unroll
        for (int o = 0; o < 16; ++o) {
            float wv = wrow[o];
            acc[2 * o]     += xc.x * wv;
            acc[2 * o + 1] += xc.y * wv;
        }
    }
#pragma unroll
    for (int o = 0; o < 16; ++o) {
        int O = chunk * 16 + o;
        float sm = par[PSMV + O], sh = par[PSHC + O];
        float2 v;
        v.x = gelu_f(sm * acc[2 * o]     + sh);
        v.y = gelu_f(sm * acc[2 * o + 1] + sh);
        *(float2*)&out[(size_t)(b * COUT + O) * HW + p0] = v;
    }
}

extern "C" void kernel_launch(void* const* d_in, const int* in_sizes, int n_in,
                              void* d_out, int out_size, void* d_ws, size_t ws_size,
                              hipStream_t stream) {
    const float* x    = (const float*)d_in[0];
    const float* w1   = (const float*)d_in[1];
    const float* wr   = (const float*)d_in[2];
    const float* gr   = (const float*)d_in[3];
    const float* br   = (const float*)d_in[4];
    const float* mr   = (const float*)d_in[5];
    const float* vr   = (const float*)d_in[6];
    const float* wsp  = (const float*)d_in[7];
    const float* bsp  = (const float*)d_in[8];
    const float* g1   = (const float*)d_in[9];
    const float* b1   = (const float*)d_in[10];
    const float* m1   = (const float*)d_in[11];
    const float* v1   = (const float*)d_in[12];
    const float* w2   = (const float*)d_in[13];
    const float* g2   = (const float*)d_in[14];
    const float* b2   = (const float*)d_in[15];
    const float* m2   = (const float*)d_in[16];
    const float* v2   = (const float*)d_in[17];
    const float* wm   = (const float*)d_in[18];
    const float* bmap = (const float*)d_in[19];
    const float* gm   = (const float*)d_in[20];
    const float* betam= (const float*)d_in[21];
    const float* mm   = (const float*)d_in[22];
    const float* vm   = (const float*)d_in[23];

    unsigned* x1pad = (unsigned*)d_ws;
    float*    rbuf  = (float*)((char*)d_ws + OFF_RBUF);
    unsigned* x2b   = (unsigned*)((char*)d_ws + OFF_X2B);
    float*    par   = (float*)((char*)d_ws + OFF_PAR);

    int nzb = (N16PAD + 255) / 256;              // 2245 zero blocks
    k0_init<<<nzb + 1, 256, 0, stream>>>(w1, wr, gr, br, mr, vr, g1, b1, m1, v1,
                                         w2, g2, b2, m2, v2, wm, bmap, gm, betam,
                                         mm, vm, par, (uint4*)x1pad);
    k1_conv1_gelu_reduce<<<Bsz * HW / 128, 256, 0, stream>>>(x, par, x1pad, rbuf);
    k23_involution<<<Bsz * GG * HW / 256, 256, 0, stream>>>(
        x1pad, rbuf, wsp, bsp, par, x2b);
    k4_final<<<Bsz * HW / 128, 256, 0, stream>>>(x2b, x, par, (float*)d_out);
}

// Round 13
// 173.196 us; speedup vs baseline: 1.2339x; 1.2339x over previous
//
#include <hip/hip_runtime.h>
#include <hip/hip_bf16.h>
#include <math.h>

#define HW    16384
#define Bsz   4
#define CIN   32
#define COUT  64
#define RED   16
#define KKN   49
#define GG    4
#define PW    134           // padded width/height (128 + 2*3)
#define PPLANE (PW*PW)
#define N16PAD 574592       // uint4 count of x1pad

typedef __hip_bfloat16 bf16;
typedef __attribute__((ext_vector_type(8))) short bf16x8;   // 8 bf16 = 4 VGPR
typedef __attribute__((ext_vector_type(4))) float f32x4;

__device__ __forceinline__ float gelu_f(float x) {
    return 0.5f * x * (1.0f + erff(x * 0.70710678118654752f));
}
__device__ __forceinline__ void unpack_bf2(unsigned u, float& lo, float& hi) {
    lo = __uint_as_float(u << 16);
    hi = __uint_as_float(u & 0xffff0000u);
}
__device__ __forceinline__ unsigned pack_bf2(float lo, float hi) {
    unsigned a = __float_as_uint(lo), b = __float_as_uint(hi);
    a += 0x7fff + ((a >> 16) & 1);
    b += 0x7fff + ((b >> 16) & 1);
    return (a >> 16) | (b & 0xffff0000u);
}
__device__ __forceinline__ unsigned short bf16r(float v) {
    unsigned a = __float_as_uint(v);
    a += 0x7fff + ((a >> 16) & 1);
    return (unsigned short)(a >> 16);
}

// ---- workspace layout (bytes) ----
#define OFF_RBUF  9437184
#define OFF_X2B   13631488
#define OFF_PAR   22020096
#define OFF_XBF   22085632          // par region is 64 KB
// par float offsets
#define PW1T 0
#define PWRT 2048
#define PRSH 3072
#define PSHC (PRSH+16)
#define PSMV (PSHC+64)
#define PSC1 (PSMV+64)
#define PSH1 (PSC1+64)
#define PCAT_F 12288                // wcat as ushort[64*96] at float offset 12288 (48 KB)

// fused init: block 0 does weight prep; remaining blocks zero x1pad halo buffer
__global__ __launch_bounds__(256) void k0_init(
    const float* __restrict__ w1, const float* __restrict__ wr,
    const float* __restrict__ gr, const float* __restrict__ br,
    const float* __restrict__ mr, const float* __restrict__ vr,
    const float* __restrict__ g1, const float* __restrict__ b1,
    const float* __restrict__ m1, const float* __restrict__ v1,
    const float* __restrict__ w2, const float* __restrict__ g2,
    const float* __restrict__ b2, const float* __restrict__ m2,
    const float* __restrict__ v2,
    const float* __restrict__ wm, const float* __restrict__ bmap,
    const float* __restrict__ gm, const float* __restrict__ betam,
    const float* __restrict__ mm, const float* __restrict__ vm,
    float* __restrict__ par, uint4* __restrict__ x1pad)
{
    if (blockIdx.x != 0) {
        int i = (blockIdx.x - 1) * 256 + threadIdx.x;
        if (i < N16PAD) x1pad[i] = make_uint4(0u, 0u, 0u, 0u);
        return;
    }
    int t = threadIdx.x;
    for (int i = t; i < 2048; i += 256) {
        int c = i >> 6, o = i & 63;
        par[PW1T + i] = w1[o * CIN + c];
    }
    for (int i = t; i < 1024; i += 256) {
        int c = i >> 4, j = i & 15;
        float sc = gr[j] * rsqrtf(vr[j] + 1e-5f);
        par[PWRT + i] = wr[j * COUT + c] * sc;
    }
    // wcat[o][c]: c<64 -> w2[o][c]*(s2/sm); c>=64 -> wm[o][c-64]   (bf16)
    unsigned short* wcat = (unsigned short*)(par + PCAT_F);
    for (int i = t; i < 64 * 96; i += 256) {
        int o = i / 96, c = i - o * 96;
        float v;
        if (c < 64) {
            float s2 = g2[o] * rsqrtf(v2[o] + 1e-5f);
            float sm = gm[o] * rsqrtf(vm[o] + 1e-5f);
            v = w2[o * COUT + c] * (s2 / sm);
        } else {
            v = wm[o * CIN + (c - 64)];
        }
        wcat[i] = bf16r(v);
    }
    if (t < 16) {
        float sc = gr[t] * rsqrtf(vr[t] + 1e-5f);
        par[PRSH + t] = br[t] - mr[t] * sc;
    }
    if (t < 64) {
        float s2 = g2[t] * rsqrtf(v2[t] + 1e-5f);
        float sm = gm[t] * rsqrtf(vm[t] + 1e-5f);
        par[PSHC + t] = (b2[t] - m2[t] * s2) + (betam[t] + (bmap[t] - mm[t]) * sm);
        par[PSMV + t] = sm;
        float s1 = g1[t] * rsqrtf(v1[t] + 1e-5f);
        par[PSC1 + t] = s1;
        par[PSH1 + t] = b1[t] - m1[t] * s1;
    }
}

// K1: round-11 structure (1 px/thread) + chunk0 stores bf16 x copy (xbf).
__global__ __launch_bounds__(256, 4) void k1_conv1_gelu_reduce(
    const float* __restrict__ x, const float* __restrict__ par,
    unsigned* __restrict__ x1pad, float* __restrict__ rbuf,
    unsigned short* __restrict__ xbf)
{
    __shared__ float g_lds[COUT][65];

    int lane  = threadIdx.x & 63;
    int chunk = __builtin_amdgcn_readfirstlane(threadIdx.x >> 6);  // == group
    int b     = blockIdx.x >> 8;
    int p     = ((blockIdx.x & 255) << 6) + lane;
    int h = p >> 7, w = p & 127;

    float xv[CIN];
#pragma unroll
    for (int c = 0; c < CIN; ++c) xv[c] = x[(b * CIN + c) * HW + p];

    if (chunk == 0) {
        unsigned pkx[16];
#pragma unroll
        for (int d = 0; d < 16; ++d) pkx[d] = pack_bf2(xv[2 * d], xv[2 * d + 1]);
        unsigned* xo2 = (unsigned*)&xbf[((size_t)(b * HW + p)) * 32];
        *(uint4*)xo2        = make_uint4(pkx[0], pkx[1], pkx[2], pkx[3]);
        *(uint4*)(xo2 + 4)  = make_uint4(pkx[4], pkx[5], pkx[6], pkx[7]);
        *(uint4*)(xo2 + 8)  = make_uint4(pkx[8], pkx[9], pkx[10], pkx[11]);
        *(uint4*)(xo2 + 12) = make_uint4(pkx[12], pkx[13], pkx[14], pkx[15]);
    }

    float acc[16];
#pragma unroll
    for (int o = 0; o < 16; ++o) acc[o] = 0.f;
#pragma unroll 8
    for (int c = 0; c < CIN; ++c) {
        float xc = xv[c];
        const float* wrow = par + PW1T + c * 64 + chunk * 16;
#pragma unroll
        for (int o = 0; o < 16; ++o) acc[o] += xc * wrow[o];
    }

    unsigned pk[8];
#pragma unroll
    for (int o = 0; o < 16; ++o) {
        acc[o] = gelu_f(acc[o]);
        g_lds[chunk * 16 + o][lane] = acc[o];
    }
#pragma unroll
    for (int d = 0; d < 8; ++d) pk[d] = pack_bf2(acc[2 * d], acc[2 * d + 1]);
    unsigned* xo = x1pad + ((size_t)((b * GG + chunk) * PW + (h + 3)) * PW + (w + 3)) * 8;
    *(uint4*)xo       = make_uint4(pk[0], pk[1], pk[2], pk[3]);
    *(uint4*)(xo + 4) = make_uint4(pk[4], pk[5], pk[6], pk[7]);

    __syncthreads();

    float ra[4] = {0.f, 0.f, 0.f, 0.f};
#pragma unroll 8
    for (int c = 0; c < COUT; ++c) {
        float gv = g_lds[c][lane];
        const float* wrow = par + PWRT + c * 16 + chunk * 4;
#pragma unroll
        for (int jj = 0; jj < 4; ++jj) ra[jj] += gv * wrow[jj];
    }
    float t[4];
#pragma unroll
    for (int jj = 0; jj < 4; ++jj)
        t[jj] = fmaxf(ra[jj] + par[PRSH + chunk * 4 + jj], 0.f);
    *(float4*)&rbuf[((size_t)b * HW + p) * 16 + chunk * 4] =
        make_float4(t[0], t[1], t[2], t[3]);
}

// K23: unchanged (round 11: runtime tap loops, zero halo).
__global__ __launch_bounds__(256, 4) void k23_involution(
    const unsigned* __restrict__ x1pad, const float* __restrict__ rbuf,
    const float* __restrict__ wsp, const float* __restrict__ bsp,
    const float* __restrict__ par, unsigned* __restrict__ x2b)
{
    int bg = blockIdx.x >> 6;
    int g = bg & 3, b = bg >> 2;
    int p = ((blockIdx.x & 63) << 8) + threadIdx.x;
    int h = p >> 7, w0 = p & 127;

    float r[RED];
    {
        const float4* rp = (const float4*)&rbuf[((size_t)b * HW + p) * 16];
        float4 r0 = rp[0], r1 = rp[1], r2 = rp[2], r3 = rp[3];
        r[0]=r0.x; r[1]=r0.y; r[2]=r0.z; r[3]=r0.w;
        r[4]=r1.x; r[5]=r1.y; r[6]=r1.z; r[7]=r1.w;
        r[8]=r2.x; r[9]=r2.y; r[10]=r2.z; r[11]=r2.w;
        r[12]=r3.x; r[13]=r3.y; r[14]=r3.z; r[15]=r3.w;
    }

    const float* wrow = wsp + g * KKN * RED;
    const float* brow = bsp + g * KKN;
    const unsigned* base = x1pad + ((size_t)(bg * PW + h) * PW + w0) * 8;

    float acc[RED];
#pragma unroll
    for (int c = 0; c < RED; ++c) acc[c] = 0.f;

#pragma unroll 1
    for (int i = 0; i < 7; ++i) {
#pragma unroll 1
        for (int j = 0; j < 7; ++j) {
            int k = i * 7 + j;
            const float* wk_row = wrow + k * RED;
            float s = brow[k];
#pragma unroll
            for (int jj = 0; jj < RED; ++jj) s += r[jj] * wk_row[jj];
            const unsigned* tp = base + (size_t)(i * PW + j) * 8;
            uint4 A = *(const uint4*)tp;
            uint4 B = *(const uint4*)(tp + 4);
            float lo, hi;
            unpack_bf2(A.x, lo, hi); acc[0] += s*lo; acc[1] += s*hi;
            unpack_bf2(A.y, lo, hi); acc[2] += s*lo; acc[3] += s*hi;
            unpack_bf2(A.z, lo, hi); acc[4] += s*lo; acc[5] += s*hi;
            unpack_bf2(A.w, lo, hi); acc[6] += s*lo; acc[7] += s*hi;
            unpack_bf2(B.x, lo, hi); acc[8] += s*lo; acc[9] += s*hi;
            unpack_bf2(B.y, lo, hi); acc[10]+= s*lo; acc[11]+= s*hi;
            unpack_bf2(B.z, lo, hi); acc[12]+= s*lo; acc[13]+= s*hi;
            unpack_bf2(B.w, lo, hi); acc[14]+= s*lo; acc[15]+= s*hi;
        }
    }

    unsigned pk[8];
#pragma unroll
    for (int d = 0; d < 8; ++d) {
        int ch0 = g * RED + 2 * d, ch1 = ch0 + 1;
        float v0 = gelu_f(par[PSC1 + ch0] * acc[2 * d]     + par[PSH1 + ch0]);
        float v1 = gelu_f(par[PSC1 + ch1] * acc[2 * d + 1] + par[PSH1 + ch1]);
        pk[d] = pack_bf2(v0, v1);
    }
    unsigned* xo = x2b + ((size_t)bg * HW + p) * 8;
    *(uint4*)xo       = make_uint4(pk[0], pk[1], pk[2], pk[3]);
    *(uint4*)(xo + 4) = make_uint4(pk[4], pk[5], pk[6], pk[7]);
}

// K4 via MFMA: out[px,o] = gelu( sm[o] * ([x2|x] . wcat)[px,o] + shc[o] )
// Wave = 16 px x 64 o, K = 96 (3 k-tiles x 4 n-tiles = 12 mfma).
// Weights in VGPRs (48), loaded once. A-frags: 1 dwordx4/lane/k-tile.
// Layouts (guide-verified): A[m=lane&15][k=quad*8+j]; B[k=quad*8+j][n=lane&15];
// D: col(o)=lane&15, row(px)=quad*4+reg.
__global__ __launch_bounds__(256, 4) void k4_mfma(
    const unsigned short* __restrict__ x2s, const unsigned short* __restrict__ xbf,
    const float* __restrict__ par, float* __restrict__ out)
{
    int lane = threadIdx.x & 63;
    int wave = threadIdx.x >> 6;
    int m15  = lane & 15;
    int quad = lane >> 4;
    int b    = blockIdx.x >> 8;
    int px0  = (((blockIdx.x & 255) << 2) + wave) << 4;   // wave's 16-px tile

    const unsigned short* wcat = (const unsigned short*)(par + PCAT_F);

    bf16x8 Bf[3][4];
#pragma unroll
    for (int kt = 0; kt < 3; ++kt)
#pragma unroll
        for (int nt = 0; nt < 4; ++nt)
            Bf[kt][nt] = *(const bf16x8*)&wcat[(nt * 16 + m15) * 96 + kt * 32 + quad * 8];

    int px = px0 + m15;
    bf16x8 Af[3];
    {
        int g0 = quad >> 1, co = (quad & 1) * 8;
        Af[0] = *(const bf16x8*)&x2s[((size_t)((b * 4 + g0) * HW + px)) * 16 + co];
        Af[1] = *(const bf16x8*)&x2s[((size_t)((b * 4 + 2 + g0) * HW + px)) * 16 + co];
        Af[2] = *(const bf16x8*)&xbf[((size_t)(b * HW + px)) * 32 + quad * 8];
    }

    f32x4 acc[4];
#pragma unroll
    for (int nt = 0; nt < 4; ++nt) acc[nt] = (f32x4){0.f, 0.f, 0.f, 0.f};
#pragma unroll
    for (int kt = 0; kt < 3; ++kt)
#pragma unroll
        for (int nt = 0; nt < 4; ++nt)
            acc[nt] = __builtin_amdgcn_mfma_f32_16x16x32_bf16(
                Af[kt], Bf[kt][nt], acc[nt], 0, 0, 0);

#pragma unroll
    for (int nt = 0; nt < 4; ++nt) {
        int o = nt * 16 + m15;
        float smv = par[PSMV + o], sh = par[PSHC + o];
        float* op = out + (size_t)(b * COUT + o) * HW + px0 + quad * 4;
#pragma unroll
        for (int reg = 0; reg < 4; ++reg)
            op[reg] = gelu_f(smv * acc[nt][reg] + sh);
    }
}

extern "C" void kernel_launch(void* const* d_in, const int* in_sizes, int n_in,
                              void* d_out, int out_size, void* d_ws, size_t ws_size,
                              hipStream_t stream) {
    const float* x    = (const float*)d_in[0];
    const float* w1   = (const float*)d_in[1];
    const float* wr   = (const float*)d_in[2];
    const float* gr   = (const float*)d_in[3];
    const float* br   = (const float*)d_in[4];
    const float* mr   = (const float*)d_in[5];
    const float* vr   = (const float*)d_in[6];
    const float* wsp  = (const float*)d_in[7];
    const float* bsp  = (const float*)d_in[8];
    const float* g1   = (const float*)d_in[9];
    const float* b1   = (const float*)d_in[10];
    const float* m1   = (const float*)d_in[11];
    const float* v1   = (const float*)d_in[12];
    const float* w2   = (const float*)d_in[13];
    const float* g2   = (const float*)d_in[14];
    const float* b2   = (const float*)d_in[15];
    const float* m2   = (const float*)d_in[16];
    const float* v2   = (const float*)d_in[17];
    const float* wm   = (const float*)d_in[18];
    const float* bmap = (const float*)d_in[19];
    const float* gm   = (const float*)d_in[20];
    const float* betam= (const float*)d_in[21];
    const float* mm   = (const float*)d_in[22];
    const float* vm   = (const float*)d_in[23];

    unsigned*       x1pad = (unsigned*)d_ws;
    float*          rbuf  = (float*)((char*)d_ws + OFF_RBUF);
    unsigned*       x2b   = (unsigned*)((char*)d_ws + OFF_X2B);
    float*          par   = (float*)((char*)d_ws + OFF_PAR);
    unsigned short* xbf   = (unsigned short*)((char*)d_ws + OFF_XBF);

    int nzb = (N16PAD + 255) / 256;
    k0_init<<<nzb + 1, 256, 0, stream>>>(w1, wr, gr, br, mr, vr, g1, b1, m1, v1,
                                         w2, g2, b2, m2, v2, wm, bmap, gm, betam,
                                         mm, vm, par, (uint4*)x1pad);
    k1_conv1_gelu_reduce<<<Bsz * HW / 64, 256, 0, stream>>>(x, par, x1pad, rbuf, xbf);
    k23_involution<<<Bsz * GG * HW / 256, 256, 0, stream>>>(
        x1pad, rbuf, wsp, bsp, par, x2b);
    k4_mfma<<<Bsz * HW / 64, 256, 0, stream>>>(
        (const unsigned short*)x2b, xbf, par, (float*)d_out);
}

// Round 14
// 170.525 us; speedup vs baseline: 1.2532x; 1.0157x over previous
//
#include <hip/hip_runtime.h>
#include <hip/hip_bf16.h>
#include <math.h>

#define HW    16384
#define Bsz   4
#define CIN   32
#define COUT  64
#define RED   16
#define KKN   49
#define GG    4
#define PW    134           // padded width/height (128 + 2*3)
#define PPLANE (PW*PW)
#define N16PAD 574592       // uint4 count of x1pad

typedef __hip_bfloat16 bf16;
typedef __attribute__((ext_vector_type(8))) short bf16x8;   // 8 bf16 = 4 VGPR
typedef __attribute__((ext_vector_type(4))) float f32x4;

__device__ __forceinline__ float gelu_f(float x) {
    return 0.5f * x * (1.0f + erff(x * 0.70710678118654752f));
}
__device__ __forceinline__ void unpack_bf2(unsigned u, float& lo, float& hi) {
    lo = __uint_as_float(u << 16);
    hi = __uint_as_float(u & 0xffff0000u);
}
__device__ __forceinline__ unsigned pack_bf2(float lo, float hi) {
    unsigned a = __float_as_uint(lo), b = __float_as_uint(hi);
    a += 0x7fff + ((a >> 16) & 1);
    b += 0x7fff + ((b >> 16) & 1);
    return (a >> 16) | (b & 0xffff0000u);
}
__device__ __forceinline__ unsigned short bf16r(float v) {
    unsigned a = __float_as_uint(v);
    a += 0x7fff + ((a >> 16) & 1);
    return (unsigned short)(a >> 16);
}

// ---- workspace layout (bytes) ----
#define OFF_RBUF  9437184
#define OFF_X2B   13631488
#define OFF_PAR   22020096
#define OFF_XBF   22085632          // par region is 64 KB
// par region: float index offsets
#define PRSH_F 0
#define PSHC_F 16
#define PSMV_F 80
#define PSC1_F 144
#define PSH1_F 208
// par region: byte offsets for bf16 tables
#define BW1B 4096                   // w1b  ushort[64][32]
#define BWRB 8192                   // wrb  ushort[16][64] (BN-scaled)
#define BCAT 12288                  // wcat ushort[64][96]

// fused init: block 0 = weight prep; blocks 1..nzb = zero x1pad; rest build xbf.
__global__ __launch_bounds__(256) void k0_init(
    const float* __restrict__ x,
    const float* __restrict__ w1, const float* __restrict__ wr,
    const float* __restrict__ gr, const float* __restrict__ br,
    const float* __restrict__ mr, const float* __restrict__ vr,
    const float* __restrict__ g1, const float* __restrict__ b1,
    const float* __restrict__ m1, const float* __restrict__ v1,
    const float* __restrict__ w2, const float* __restrict__ g2,
    const float* __restrict__ b2, const float* __restrict__ m2,
    const float* __restrict__ v2,
    const float* __restrict__ wm, const float* __restrict__ bmap,
    const float* __restrict__ gm, const float* __restrict__ betam,
    const float* __restrict__ mm, const float* __restrict__ vm,
    char* __restrict__ parb, uint4* __restrict__ x1pad,
    unsigned short* __restrict__ xbf, int nzb)
{
    int bid = blockIdx.x, t = threadIdx.x;
    if (bid >= 1 && bid <= nzb) {
        int i = (bid - 1) * 256 + t;
        if (i < N16PAD) x1pad[i] = make_uint4(0u, 0u, 0u, 0u);
        return;
    }
    if (bid > nzb) {
        // xbf builder: 256 px per block, [b][px][c32] bf16
        int gpx = (bid - nzb - 1) * 256 + t;        // [0, Bsz*HW)
        int b = gpx >> 14, p = gpx & (HW - 1);
        float xv[CIN];
#pragma unroll
        for (int c = 0; c < CIN; ++c) xv[c] = x[(b * CIN + c) * HW + p];
        unsigned pk[16];
#pragma unroll
        for (int d = 0; d < 16; ++d) pk[d] = pack_bf2(xv[2 * d], xv[2 * d + 1]);
        unsigned* xo = (unsigned*)&xbf[(size_t)gpx * 32];
        *(uint4*)xo        = make_uint4(pk[0], pk[1], pk[2], pk[3]);
        *(uint4*)(xo + 4)  = make_uint4(pk[4], pk[5], pk[6], pk[7]);
        *(uint4*)(xo + 8)  = make_uint4(pk[8], pk[9], pk[10], pk[11]);
        *(uint4*)(xo + 12) = make_uint4(pk[12], pk[13], pk[14], pk[15]);
        return;
    }
    // bid == 0: weight prep
    float* parf = (float*)parb;
    unsigned short* w1b  = (unsigned short*)(parb + BW1B);
    unsigned short* wrb  = (unsigned short*)(parb + BWRB);
    unsigned short* wcat = (unsigned short*)(parb + BCAT);
    for (int i = t; i < 64 * 32; i += 256)
        w1b[i] = bf16r(w1[i]);                       // [o][c] already B-friendly
    for (int i = t; i < 16 * 64; i += 256) {
        int j = i >> 6;
        float sc = gr[j] * rsqrtf(vr[j] + 1e-5f);
        wrb[i] = bf16r(wr[i] * sc);                  // [j][c], BN-scale folded
    }
    for (int i = t; i < 64 * 96; i += 256) {
        int o = i / 96, c = i - o * 96;
        float v;
        if (c < 64) {
            float s2 = g2[o] * rsqrtf(v2[o] + 1e-5f);
            float sm = gm[o] * rsqrtf(vm[o] + 1e-5f);
            v = w2[o * COUT + c] * (s2 / sm);
        } else {
            v = wm[o * CIN + (c - 64)];
        }
        wcat[i] = bf16r(v);
    }
    if (t < 16) {
        float sc = gr[t] * rsqrtf(vr[t] + 1e-5f);
        parf[PRSH_F + t] = br[t] - mr[t] * sc;
    }
    if (t < 64) {
        float s2 = g2[t] * rsqrtf(v2[t] + 1e-5f);
        float sm = gm[t] * rsqrtf(vm[t] + 1e-5f);
        parf[PSHC_F + t] = (b2[t] - m2[t] * s2) + (betam[t] + (bmap[t] - mm[t]) * sm);
        parf[PSMV_F + t] = sm;
        float s1 = g1[t] * rsqrtf(v1[t] + 1e-5f);
        parf[PSC1_F + t] = s1;
        parf[PSH1_F + t] = b1[t] - m1[t] * s1;
    }
}

// K1 via MFMA: x1 = gelu(xbf . w1^T) -> x1pad (bf16 interleaved);
//              r  = relu(x1 . wr_scaled^T + rsh) -> rbuf [b][p][j16].
// Wave = 16 px. conv1: K=32 -> 4 mfma. reduce: K=64 -> 2 mfma.
// gelu(x1) transits a per-wave LDS tile to re-enter A-layout (k4-verified maps).
__global__ __launch_bounds__(256, 4) void k1_mfma(
    const unsigned short* __restrict__ xbf, const char* __restrict__ parb,
    unsigned* __restrict__ x1pad, float* __restrict__ rbuf)
{
    __shared__ float x1f[4][16][65];

    int lane = threadIdx.x & 63;
    int wave = threadIdx.x >> 6;
    int m15 = lane & 15, quad = lane >> 4;
    int base_gpx = blockIdx.x * 64 + wave * 16;     // 64 px per block, 16 per wave
    int b   = base_gpx >> 14;
    int px0 = base_gpx & (HW - 1);

    const unsigned short* w1b = (const unsigned short*)(parb + BW1B);
    const unsigned short* wrb = (const unsigned short*)(parb + BWRB);
    const float* parf = (const float*)parb;

    // conv1: A[m=px][k=c], B[k=c][n=o] from w1b[o][c] rows
    bf16x8 Af = *(const bf16x8*)&xbf[((size_t)(base_gpx + m15)) * 32 + quad * 8];
    f32x4 acc[4];
#pragma unroll
    for (int nt = 0; nt < 4; ++nt) {
        bf16x8 Bf = *(const bf16x8*)&w1b[(nt * 16 + m15) * 32 + quad * 8];
        f32x4 z = {0.f, 0.f, 0.f, 0.f};
        acc[nt] = __builtin_amdgcn_mfma_f32_16x16x32_bf16(Af, Bf, z, 0, 0, 0);
    }
    // gelu + stage to LDS (D: row px=quad*4+reg, col o=nt*16+m15)
#pragma unroll
    for (int nt = 0; nt < 4; ++nt)
#pragma unroll
        for (int reg = 0; reg < 4; ++reg)
            x1f[wave][quad * 4 + reg][nt * 16 + m15] = gelu_f(acc[nt][reg]);

    __syncthreads();

    // x1pad store: lane l -> px=l>>2, group g=l&3 (16 ch contiguous bf16)
    {
        int pxl = lane >> 2, g = lane & 3;
        int p = px0 + pxl, h = p >> 7, w = p & 127;
        unsigned pk[8];
#pragma unroll
        for (int d = 0; d < 8; ++d)
            pk[d] = pack_bf2(x1f[wave][pxl][g * 16 + 2 * d],
                             x1f[wave][pxl][g * 16 + 2 * d + 1]);
        unsigned* xo = x1pad +
            ((size_t)((b * GG + g) * PW + (h + 3)) * PW + (w + 3)) * 8;
        *(uint4*)xo       = make_uint4(pk[0], pk[1], pk[2], pk[3]);
        *(uint4*)(xo + 4) = make_uint4(pk[4], pk[5], pk[6], pk[7]);
    }

    // reduce: A[m=px][k=c] from LDS (bf16 repack), B[k=c][n=j] from wrb[j][c]
    f32x4 racc = {0.f, 0.f, 0.f, 0.f};
#pragma unroll
    for (int kt = 0; kt < 2; ++kt) {
        bf16x8 A2, B2;
#pragma unroll
        for (int j = 0; j < 8; ++j)
            A2[j] = (short)bf16r(x1f[wave][m15][kt * 32 + quad * 8 + j]);
        B2 = *(const bf16x8*)&wrb[m15 * 64 + kt * 32 + quad * 8];
        racc = __builtin_amdgcn_mfma_f32_16x16x32_bf16(A2, B2, racc, 0, 0, 0);
    }
    // D: row px=quad*4+reg, col j=m15. relu + shift, store rbuf [px][j16]
    float rsh = parf[PRSH_F + m15];
#pragma unroll
    for (int reg = 0; reg < 4; ++reg) {
        int gp = base_gpx + quad * 4 + reg;
        rbuf[(size_t)gp * 16 + m15] = fmaxf(racc[reg] + rsh, 0.f);
    }
}

// K23: unchanged (round 11: runtime tap loops, zero halo).
__global__ __launch_bounds__(256, 4) void k23_involution(
    const unsigned* __restrict__ x1pad, const float* __restrict__ rbuf,
    const float* __restrict__ wsp, const float* __restrict__ bsp,
    const float* __restrict__ par, unsigned* __restrict__ x2b)
{
    int bg = blockIdx.x >> 6;
    int g = bg & 3, b = bg >> 2;
    int p = ((blockIdx.x & 63) << 8) + threadIdx.x;
    int h = p >> 7, w0 = p & 127;

    float r[RED];
    {
        const float4* rp = (const float4*)&rbuf[((size_t)b * HW + p) * 16];
        float4 r0 = rp[0], r1 = rp[1], r2 = rp[2], r3 = rp[3];
        r[0]=r0.x; r[1]=r0.y; r[2]=r0.z; r[3]=r0.w;
        r[4]=r1.x; r[5]=r1.y; r[6]=r1.z; r[7]=r1.w;
        r[8]=r2.x; r[9]=r2.y; r[10]=r2.z; r[11]=r2.w;
        r[12]=r3.x; r[13]=r3.y; r[14]=r3.z; r[15]=r3.w;
    }

    const float* wrow = wsp + g * KKN * RED;
    const float* brow = bsp + g * KKN;
    const unsigned* base = x1pad + ((size_t)(bg * PW + h) * PW + w0) * 8;

    float acc[RED];
#pragma unroll
    for (int c = 0; c < RED; ++c) acc[c] = 0.f;

#pragma unroll 1
    for (int i = 0; i < 7; ++i) {
#pragma unroll 1
        for (int j = 0; j < 7; ++j) {
            int k = i * 7 + j;
            const float* wk_row = wrow + k * RED;
            float s = brow[k];
#pragma unroll
            for (int jj = 0; jj < RED; ++jj) s += r[jj] * wk_row[jj];
            const unsigned* tp = base + (size_t)(i * PW + j) * 8;
            uint4 A = *(const uint4*)tp;
            uint4 B = *(const uint4*)(tp + 4);
            float lo, hi;
            unpack_bf2(A.x, lo, hi); acc[0] += s*lo; acc[1] += s*hi;
            unpack_bf2(A.y, lo, hi); acc[2] += s*lo; acc[3] += s*hi;
            unpack_bf2(A.z, lo, hi); acc[4] += s*lo; acc[5] += s*hi;
            unpack_bf2(A.w, lo, hi); acc[6] += s*lo; acc[7] += s*hi;
            unpack_bf2(B.x, lo, hi); acc[8] += s*lo; acc[9] += s*hi;
            unpack_bf2(B.y, lo, hi); acc[10]+= s*lo; acc[11]+= s*hi;
            unpack_bf2(B.z, lo, hi); acc[12]+= s*lo; acc[13]+= s*hi;
            unpack_bf2(B.w, lo, hi); acc[14]+= s*lo; acc[15]+= s*hi;
        }
    }

    unsigned pk[8];
#pragma unroll
    for (int d = 0; d < 8; ++d) {
        int ch0 = g * RED + 2 * d, ch1 = ch0 + 1;
        float v0 = gelu_f(par[PSC1_F + ch0] * acc[2 * d]     + par[PSH1_F + ch0]);
        float v1 = gelu_f(par[PSC1_F + ch1] * acc[2 * d + 1] + par[PSH1_F + ch1]);
        pk[d] = pack_bf2(v0, v1);
    }
    unsigned* xo = x2b + ((size_t)bg * HW + p) * 8;
    *(uint4*)xo       = make_uint4(pk[0], pk[1], pk[2], pk[3]);
    *(uint4*)(xo + 4) = make_uint4(pk[4], pk[5], pk[6], pk[7]);
}

// K4 via MFMA (round 13, verified): out = gelu(sm*([x2|x].wcat) + shc)
__global__ __launch_bounds__(256, 4) void k4_mfma(
    const unsigned short* __restrict__ x2s, const unsigned short* __restrict__ xbf,
    const char* __restrict__ parb, float* __restrict__ out)
{
    int lane = threadIdx.x & 63;
    int wave = threadIdx.x >> 6;
    int m15  = lane & 15;
    int quad = lane >> 4;
    int b    = blockIdx.x >> 8;
    int px0  = (((blockIdx.x & 255) << 2) + wave) << 4;

    const unsigned short* wcat = (const unsigned short*)(parb + BCAT);
    const float* parf = (const float*)parb;

    bf16x8 Bf[3][4];
#pragma unroll
    for (int kt = 0; kt < 3; ++kt)
#pragma unroll
        for (int nt = 0; nt < 4; ++nt)
            Bf[kt][nt] = *(const bf16x8*)&wcat[(nt * 16 + m15) * 96 + kt * 32 + quad * 8];

    int px = px0 + m15;
    bf16x8 Af[3];
    {
        int g0 = quad >> 1, co = (quad & 1) * 8;
        Af[0] = *(const bf16x8*)&x2s[((size_t)((b * 4 + g0) * HW + px)) * 16 + co];
        Af[1] = *(const bf16x8*)&x2s[((size_t)((b * 4 + 2 + g0) * HW + px)) * 16 + co];
        Af[2] = *(const bf16x8*)&xbf[((size_t)(b * HW + px)) * 32 + quad * 8];
    }

    f32x4 acc[4];
#pragma unroll
    for (int nt = 0; nt < 4; ++nt) acc[nt] = (f32x4){0.f, 0.f, 0.f, 0.f};
#pragma unroll
    for (int kt = 0; kt < 3; ++kt)
#pragma unroll
        for (int nt = 0; nt < 4; ++nt)
            acc[nt] = __builtin_amdgcn_mfma_f32_16x16x32_bf16(
                Af[kt], Bf[kt][nt], acc[nt], 0, 0, 0);

#pragma unroll
    for (int nt = 0; nt < 4; ++nt) {
        int o = nt * 16 + m15;
        float smv = parf[PSMV_F + o], sh = parf[PSHC_F + o];
        float* op = out + (size_t)(b * COUT + o) * HW + px0 + quad * 4;
#pragma unroll
        for (int reg = 0; reg < 4; ++reg)
            op[reg] = gelu_f(smv * acc[nt][reg] + sh);
    }
}

extern "C" void kernel_launch(void* const* d_in, const int* in_sizes, int n_in,
                              void* d_out, int out_size, void* d_ws, size_t ws_size,
                              hipStream_t stream) {
    const float* x    = (const float*)d_in[0];
    const float* w1   = (const float*)d_in[1];
    const float* wr   = (const float*)d_in[2];
    const float* gr   = (const float*)d_in[3];
    const float* br   = (const float*)d_in[4];
    const float* mr   = (const float*)d_in[5];
    const float* vr   = (const float*)d_in[6];
    const float* wsp  = (const float*)d_in[7];
    const float* bsp  = (const float*)d_in[8];
    const float* g1   = (const float*)d_in[9];
    const float* b1   = (const float*)d_in[10];
    const float* m1   = (const float*)d_in[11];
    const float* v1   = (const float*)d_in[12];
    const float* w2   = (const float*)d_in[13];
    const float* g2   = (const float*)d_in[14];
    const float* b2   = (const float*)d_in[15];
    const float* m2   = (const float*)d_in[16];
    const float* v2   = (const float*)d_in[17];
    const float* wm   = (const float*)d_in[18];
    const float* bmap = (const float*)d_in[19];
    const float* gm   = (const float*)d_in[20];
    const float* betam= (const float*)d_in[21];
    const float* mm   = (const float*)d_in[22];
    const float* vm   = (const float*)d_in[23];

    unsigned*       x1pad = (unsigned*)d_ws;
    float*          rbuf  = (float*)((char*)d_ws + OFF_RBUF);
    unsigned*       x2b   = (unsigned*)((char*)d_ws + OFF_X2B);
    char*           parb  = (char*)d_ws + OFF_PAR;
    unsigned short* xbf   = (unsigned short*)((char*)d_ws + OFF_XBF);

    int nzb = (N16PAD + 255) / 256;              // 2245 zero blocks
    int nxb = Bsz * HW / 256;                    // 256 xbf blocks
    k0_init<<<1 + nzb + nxb, 256, 0, stream>>>(
        x, w1, wr, gr, br, mr, vr, g1, b1, m1, v1,
        w2, g2, b2, m2, v2, wm, bmap, gm, betam, mm, vm,
        parb, (uint4*)x1pad, xbf, nzb);
    k1_mfma<<<Bsz * HW / 64, 256, 0, stream>>>(xbf, parb, x1pad, rbuf);
    k23_involution<<<Bsz * GG * HW / 256, 256, 0, stream>>>(
        x1pad, rbuf, wsp, bsp, (const float*)parb, x2b);
    k4_mfma<<<Bsz * HW / 64, 256, 0, stream>>>(
        (const unsigned short*)x2b, xbf, parb, (float*)d_out);
}